// Round 1
// baseline (7322.543 us; speedup 1.0000x reference)
//
#include <hip/hip_runtime.h>

// Problem constants (match reference)
#define TT 4096   // sequence length (torch "batch" acting as time)
#define SD 64     // shared features
#define PD 8      // per-device features
#define DD 32     // devices
#define HH 128    // hidden
#define NG 512    // 4*H gate rows
#define XD 72     // S+P
#define XPAIRS 36 // packed f16x2 pairs of x
#define WROW 37   // padded row stride (uints) for W_ih0 in LDS (fallback path)
#define GXTB 16   // t-tile of the gx precompute kernel

typedef _Float16 h2 __attribute__((ext_vector_type(2)));
typedef unsigned uv16 __attribute__((ext_vector_type(16)));
typedef unsigned uv4 __attribute__((ext_vector_type(4)));

#if defined(__has_builtin)
#  if __has_builtin(__builtin_amdgcn_fdot2)
#    define USE_DOT2 1
#  endif
#endif

// ---- X-macro machinery: 64 indices, and 16 quads (group, 4 indices) ----
#define LIST64(X) \
  X(0) X(1) X(2) X(3) X(4) X(5) X(6) X(7) \
  X(8) X(9) X(10) X(11) X(12) X(13) X(14) X(15) \
  X(16) X(17) X(18) X(19) X(20) X(21) X(22) X(23) \
  X(24) X(25) X(26) X(27) X(28) X(29) X(30) X(31) \
  X(32) X(33) X(34) X(35) X(36) X(37) X(38) X(39) \
  X(40) X(41) X(42) X(43) X(44) X(45) X(46) X(47) \
  X(48) X(49) X(50) X(51) X(52) X(53) X(54) X(55) \
  X(56) X(57) X(58) X(59) X(60) X(61) X(62) X(63)

#define QUADS16(X) \
  X(0,0,1,2,3)     X(1,4,5,6,7)     X(2,8,9,10,11)   X(3,12,13,14,15) \
  X(4,16,17,18,19) X(5,20,21,22,23) X(6,24,25,26,27) X(7,28,29,30,31) \
  X(8,32,33,34,35) X(9,36,37,38,39) X(10,40,41,42,43) X(11,44,45,46,47) \
  X(12,48,49,50,51) X(13,52,53,54,55) X(14,56,57,58,59) X(15,60,61,62,63)

// pack two floats into one uint of f16x2 (a = low element), RTE
__device__ __forceinline__ unsigned pack_h2(float a, float b) {
  unsigned short ua = __builtin_bit_cast(unsigned short, (_Float16)a);
  unsigned short ub = __builtin_bit_cast(unsigned short, (_Float16)b);
  return ((unsigned)ub << 16) | ua;
}
__device__ __forceinline__ unsigned short f16bits(float a) {
  return __builtin_bit_cast(unsigned short, (_Float16)a);
}
__device__ __forceinline__ float f16val(unsigned short u) {
  return (float)__builtin_bit_cast(_Float16, u);
}

// acc += dot(f16x2 w, f16x2 h), fp32 accumulate (v_dot2_f32_f16)
__device__ __forceinline__ float dot2(unsigned w, unsigned h, float acc) {
#ifdef USE_DOT2
  return __builtin_amdgcn_fdot2(__builtin_bit_cast(h2, w),
                                __builtin_bit_cast(h2, h), acc, false);
#else
  h2 wv = __builtin_bit_cast(h2, w), hv = __builtin_bit_cast(h2, h);
  return __builtin_fmaf((float)wv[1], (float)hv[1],
                        __builtin_fmaf((float)wv[0], (float)hv[0], acc));
#endif
}

__device__ __forceinline__ float fast_sigmoid(float x) {
  return 1.0f / (1.0f + __expf(-x));
}
__device__ __forceinline__ float fast_tanh(float x) {
  return 2.0f / (1.0f + __expf(-2.0f * x)) - 1.0f;
}

// ---------------------------------------------------------------------------
// gx precompute: gx[d][t][g] = f16( b0[d][g] + W_ih0[d][g][:] . x[d][t][:] )
// ---------------------------------------------------------------------------
__global__ __launch_bounds__(512)
void gx_kernel(const float* __restrict__ shared_in,  // [T, S]
               const float* __restrict__ perdev,     // [D, T, P]
               const float* __restrict__ Wih0,       // [D, 4H, S+P]
               const float* __restrict__ b0,         // [D, 4H]
               unsigned short* __restrict__ gx)      // [D, T, 4H] f16
{
  const int d = blockIdx.y;
  const int t0 = blockIdx.x * GXTB;
  const int g = threadIdx.x;

  __shared__ unsigned xs[GXTB * XPAIRS];  // x tile, packed f16x2

  const float* p = Wih0 + (size_t)(d * NG + g) * XD;
  uv16 w0, w1;
  uv4 w2;
#pragma unroll
  for (int j = 0; j < 16; ++j) w0[j] = pack_h2(p[2 * j], p[2 * j + 1]);
#pragma unroll
  for (int j = 0; j < 16; ++j) w1[j] = pack_h2(p[32 + 2 * j], p[33 + 2 * j]);
#pragma unroll
  for (int j = 0; j < 4; ++j) w2[j] = pack_h2(p[64 + 2 * j], p[65 + 2 * j]);
  const float b0g = b0[d * NG + g];

  for (int i = g; i < GXTB * XPAIRS; i += 512) {
    int r = i / XPAIRS, j = i - r * XPAIRS, t = t0 + r;
    float a, b;
    if (j < SD / 2) {
      a = shared_in[t * SD + 2 * j];
      b = shared_in[t * SD + 2 * j + 1];
    } else {
      int k = 2 * (j - SD / 2);
      a = perdev[((size_t)d * TT + t) * PD + k];
      b = perdev[((size_t)d * TT + t) * PD + k + 1];
    }
    xs[i] = pack_h2(a, b);
  }
  __syncthreads();

#define WJ(j) ((j) < 16 ? w0[(j)] : ((j) < 32 ? w1[(j)-16] : w2[(j)-32]))
  for (int tt = 0; tt < GXTB; ++tt) {
    const unsigned* xr = &xs[tt * XPAIRS];
    float a0 = b0g, a1 = 0.f, a2 = 0.f, a3 = 0.f;
#pragma unroll
    for (int j = 0; j < XPAIRS; j += 4) {
      a0 = dot2(WJ(j + 0), xr[j + 0], a0);
      a1 = dot2(WJ(j + 1), xr[j + 1], a1);
      a2 = dot2(WJ(j + 2), xr[j + 2], a2);
      a3 = dot2(WJ(j + 3), xr[j + 3], a3);
    }
    gx[((size_t)d * TT + t0 + tt) * NG + g] = f16bits((a0 + a1) + (a2 + a3));
  }
#undef WJ
}

// ---------------------------------------------------------------------------
// NEW: layer-pipelined recurrence (PRE path).
//
// gates1(t) depends on h0(t) and h1(t-1); gates0(t+1) depends on h0(t).
// Both consume the SAME h0(t) -> layer0@t+1 and layer1@t run CONCURRENTLY
// in different wave groups of one 768-thread block (12 waves, 3/SIMD):
//   alpha = tid   0..255 : two layer-0 rows (g, g+256) -> 128 w-uints, 128 dot2
//   beta  = tid 256..767 : one layer-1 row (Wih1+Whh1) -> 128 w-uints, 128 dot2
// Per step: phase1 (all dots, both groups) -> barrier -> phase2 (both cell
// updates) -> barrier. 2 barriers/step instead of 3, per-thread serial dot
// work 192 -> 128, and each SIMD carries 1 alpha + 2 beta waves (balanced).
//
// VGPR budget: 768 threads = 12 waves/CU = 3 waves/EU -> 512/3 = 170 VGPRs.
// 128 weight uints as INDIVIDUAL scalar SSA values (no tuples) +
// amdgpu_waves_per_eu(3,3) to pin the RA budget at 170 (the prior-session
// lesson: the explicit MAX is what sets the budget).
// ---------------------------------------------------------------------------
__global__ __attribute__((amdgpu_flat_work_group_size(768, 768), amdgpu_waves_per_eu(3, 3)))
void lstm_pipe_kernel(const float* __restrict__ Whh0,        // [D, 4H, H]
                      const float* __restrict__ Wih1,        // [D, 4H, H]
                      const float* __restrict__ Whh1,        // [D, 4H, H]
                      const float* __restrict__ b1,          // [D, 4H]
                      const float* __restrict__ Wout,        // [D, H]
                      const float* __restrict__ bout,        // [D]
                      const unsigned short* __restrict__ gx, // [D, T, 4H] f16
                      float* __restrict__ out)               // [T, D]
{
  const int d = blockIdx.x;
  const int tid = threadIdx.x;
  const bool alpha = (tid < 256);

  __shared__ float act0_s[NG];
  __shared__ float act1_s[NG];
  __shared__ __align__(16) unsigned h0_s[HH / 2];  // h0 packed f16x2
  __shared__ __align__(16) unsigned h1_s[HH / 2];  // h1 packed f16x2
  __shared__ float part_s[2];

  // ---- weight registers: 128 independent scalars, group-dependent source ----
#define DW(n) unsigned wa##n, wb##n;
  LIST64(DW)
#undef DW
  {
    const float* pA = alpha ? (Whh0 + (size_t)(d * NG + tid) * HH)
                            : (Wih1 + (size_t)(d * NG + (tid - 256)) * HH);
    const float* pB = alpha ? (Whh0 + (size_t)(d * NG + tid + 256) * HH)
                            : (Whh1 + (size_t)(d * NG + (tid - 256)) * HH);
#define SW(n) wa##n = pack_h2(pA[2 * (n)], pA[2 * (n) + 1]); \
              wb##n = pack_h2(pB[2 * (n)], pB[2 * (n) + 1]);
    LIST64(SW)
#undef SW
  }

  const float b1g   = (!alpha) ? b1[d * NG + (tid - 256)] : 0.f;
  const float woutu = (!alpha && tid < 256 + HH) ? Wout[d * HH + (tid - 256)] : 0.f;
  const float boutd = bout[d];
  float cst = 0.f;  // alpha(tid<128): c0 ; beta(256<=tid<384): c1

  if (tid < HH / 2) { h0_s[tid] = 0u; h1_s[tid] = 0u; }

  // gx prefetch (alpha only)
  unsigned short gxcA = 0, gxcB = 0, gxnA = 0, gxnB = 0;
  if (alpha) {
    gxcA = gx[(size_t)d * TT * NG + tid];
    gxcB = gx[(size_t)d * TT * NG + tid + 256];
  }

  __syncthreads();

  // iteration k: alpha computes act0(k) [k<TT]; beta computes act1(k-1) [k>=1]
  for (int k = 0; k <= TT; ++k) {
    // ---- phase 1: all gate dot-products ----
    if (alpha) {
      if (k < TT) {
        if (k + 1 < TT) {  // issue next-step gx loads early; latency hides under dots
          gxnA = gx[((size_t)d * TT + (k + 1)) * NG + tid];
          gxnB = gx[((size_t)d * TT + (k + 1)) * NG + tid + 256];
        }
        float aa0 = f16val(gxcA), aa1 = 0.f, aa2 = 0.f, aa3 = 0.f;
        float bb0 = f16val(gxcB), bb1 = 0.f, bb2 = 0.f, bb3 = 0.f;
        const uint4* h4 = (const uint4*)h0_s;
#define DA(q, n0, n1, n2, n3) { \
        uint4 hv = h4[q]; \
        aa0 = dot2(wa##n0, hv.x, aa0); aa1 = dot2(wa##n1, hv.y, aa1); \
        aa2 = dot2(wa##n2, hv.z, aa2); aa3 = dot2(wa##n3, hv.w, aa3); \
        bb0 = dot2(wb##n0, hv.x, bb0); bb1 = dot2(wb##n1, hv.y, bb1); \
        bb2 = dot2(wb##n2, hv.z, bb2); bb3 = dot2(wb##n3, hv.w, bb3); }
        QUADS16(DA)
#undef DA
        float preA = (aa0 + aa1) + (aa2 + aa3);
        float preB = (bb0 + bb1) + (bb2 + bb3);
        act0_s[tid]       = fast_sigmoid(preA);              // rows 0..255: i,f gates
        act0_s[tid + 256] = (tid < 128) ? fast_tanh(preB)    // rows 256..383: g gate
                                        : fast_sigmoid(preB);// rows 384..511: o gate
      }
      if (tid == 0 && k >= 2)  // deferred output store for t = k-2
        out[(size_t)(k - 2) * DD + d] = part_s[0] + part_s[1] + boutd;
    } else if (k >= 1) {
      const int g = tid - 256;
      float aa0 = b1g, aa1 = 0.f, aa2 = 0.f, aa3 = 0.f;
      float bb0 = 0.f, bb1 = 0.f, bb2 = 0.f, bb3 = 0.f;
      const uint4* h4 = (const uint4*)h0_s;
      const uint4* g4 = (const uint4*)h1_s;
#define DB(q, n0, n1, n2, n3) { \
      uint4 hv = h4[q]; uint4 gv = g4[q]; \
      aa0 = dot2(wa##n0, hv.x, aa0); aa1 = dot2(wa##n1, hv.y, aa1); \
      aa2 = dot2(wa##n2, hv.z, aa2); aa3 = dot2(wa##n3, hv.w, aa3); \
      bb0 = dot2(wb##n0, gv.x, bb0); bb1 = dot2(wb##n1, gv.y, bb1); \
      bb2 = dot2(wb##n2, gv.z, bb2); bb3 = dot2(wb##n3, gv.w, bb3); }
      QUADS16(DB)
#undef DB
      float pre = ((aa0 + aa1) + (aa2 + aa3)) + ((bb0 + bb1) + (bb2 + bb3));
      act1_s[g] = ((g >> 7) == 2) ? fast_tanh(pre) : fast_sigmoid(pre);
    }
    __syncthreads();  // barrier A

    // ---- phase 2: cell updates (both layers concurrently) ----
    if (alpha) {
      if (tid < HH && k < TT) {
        float ig = act0_s[tid], fg = act0_s[tid + 128];
        float gg = act0_s[tid + 256], og = act0_s[tid + 384];
        cst = __builtin_fmaf(fg, cst, ig * gg);
        ((unsigned short*)h0_s)[tid] = f16bits(og * fast_tanh(cst));
      }
      gxcA = gxnA;
      gxcB = gxnB;
    } else if (tid < 256 + HH && k >= 1) {
      const int j = tid - 256;
      float ig = act1_s[j], fg = act1_s[j + 128];
      float gg = act1_s[j + 256], og = act1_s[j + 384];
      cst = __builtin_fmaf(fg, cst, ig * gg);
      float h1n = og * fast_tanh(cst);
      ((unsigned short*)h1_s)[j] = f16bits(h1n);
      float p = woutu * h1n;
#pragma unroll
      for (int off = 32; off > 0; off >>= 1) p += __shfl_down(p, off, 64);
      if ((tid & 63) == 0) part_s[(tid >> 6) - 4] = p;  // waves 4,5 -> slots 0,1
    }
    __syncthreads();  // barrier B
  }

  if (tid == 0) out[(size_t)(TT - 1) * DD + d] = part_s[0] + part_s[1] + boutd;
}

// ---------------------------------------------------------------------------
// Fallback (no workspace): previous-session kernel, non-PRE path only.
// ---------------------------------------------------------------------------
template <bool PRE>
__global__ __attribute__((amdgpu_flat_work_group_size(512, 512), amdgpu_waves_per_eu(2, 2)))
void lstm_pd_kernel(const float* __restrict__ shared_in,   // [T, S]
                    const float* __restrict__ perdev,      // [D, T, P]
                    const float* __restrict__ Wih0,        // [D, 4H, S+P]
                    const float* __restrict__ Whh0,        // [D, 4H, H]
                    const float* __restrict__ b0,          // [D, 4H]
                    const float* __restrict__ Wih1,        // [D, 4H, H]
                    const float* __restrict__ Whh1,        // [D, 4H, H]
                    const float* __restrict__ b1,          // [D, 4H]
                    const float* __restrict__ Wout,        // [D, H]
                    const float* __restrict__ bout,        // [D]
                    const unsigned short* __restrict__ gx, // [D, T, 4H] f16 (PRE)
                    float* __restrict__ out)               // [T, D]
{
  const int d = blockIdx.x;        // device
  const int g = threadIdx.x;       // gate row 0..511
  const int lane = g & 63;
  const int wave = g >> 6;

  __shared__ float act0_s[NG];
  __shared__ float act1_s[NG];
  __shared__ __align__(16) unsigned h0_s[HH / 2];      // h0 packed f16x2
  __shared__ __align__(16) unsigned h1_s[HH / 2];      // h1 packed f16x2
  __shared__ __align__(16) unsigned x_s[PRE ? 4 : (XPAIRS + 4)];
  __shared__ unsigned wih0_s[PRE ? 1 : (NG * WROW)];
  __shared__ float part_s[2];

  // ---- weight registers: 192 independent scalars ----
#define DW(n) unsigned wa##n, wi##n, wh##n;
  LIST64(DW)
#undef DW
  {
    const float* pa = Whh0 + (size_t)(d * NG + g) * HH;
    const float* pi = Wih1 + (size_t)(d * NG + g) * HH;
    const float* ph = Whh1 + (size_t)(d * NG + g) * HH;
#define SW(n) wa##n = pack_h2(pa[2 * (n)], pa[2 * (n) + 1]); \
              wi##n = pack_h2(pi[2 * (n)], pi[2 * (n) + 1]); \
              wh##n = pack_h2(ph[2 * (n)], ph[2 * (n) + 1]);
    LIST64(SW)
#undef SW
  }

  float b0g = 0.f;
  if (!PRE) {
    const float* p = Wih0 + (size_t)(d * NG + g) * XD;
    for (int j = 0; j < XPAIRS; ++j) wih0_s[g * WROW + j] = pack_h2(p[2 * j], p[2 * j + 1]);
    b0g = b0[d * NG + g];
  }
  const float b1g = b1[d * NG + g];
  const bool is_tanh_gate = ((g >> 7) == 2);  // rows 256..383 = candidate gate
  float c0 = 0.f, c1 = 0.f;
  const float woutu = (g < HH) ? Wout[d * HH + g] : 0.f;
  const float boutd = bout[d];

  if (g < HH / 2) { h0_s[g] = 0u; h1_s[g] = 0u; }

  // prefetch x-path for t=0
  unsigned short gxc = 0, gxn = 0;
  float xa = 0.f, xb = 0.f;
  if (PRE) {
    gxc = gx[((size_t)d * TT + 0) * NG + g];
  } else if (g < XPAIRS) {
    if (g < SD / 2) {
      xa = shared_in[0 * SD + 2 * g];
      xb = shared_in[0 * SD + 2 * g + 1];
    } else {
      int k = 2 * (g - SD / 2);
      xa = perdev[((size_t)d * TT + 0) * PD + k];
      xb = perdev[((size_t)d * TT + 0) * PD + k + 1];
    }
  }

  __syncthreads();

  for (int t = 0; t < TT; ++t) {
    if (!PRE) {
      if (g < XPAIRS) x_s[g] = pack_h2(xa, xb);
      __syncthreads();  // barrier 1 (fallback only)
    }

    // ---- phase 2: gates0[g] = gx + Whh0_row . h0 ----
    float a0, a1 = 0.f, a2 = 0.f, a3 = 0.f;
    if (PRE) {
      a0 = f16val(gxc);
    } else {
      a0 = b0g;
      const unsigned* wrow = &wih0_s[g * WROW];
#pragma unroll
      for (int j = 0; j < XPAIRS; j += 4) {
        a0 = dot2(wrow[j + 0], x_s[j + 0], a0);
        a1 = dot2(wrow[j + 1], x_s[j + 1], a1);
        a2 = dot2(wrow[j + 2], x_s[j + 2], a2);
        a3 = dot2(wrow[j + 3], x_s[j + 3], a3);
      }
    }
    {
      const uint4* h4 = (const uint4*)h0_s;
#define DA(q, n0, n1, n2, n3) { \
      uint4 hv = h4[q]; \
      a0 = dot2(wa##n0, hv.x, a0); a1 = dot2(wa##n1, hv.y, a1); \
      a2 = dot2(wa##n2, hv.z, a2); a3 = dot2(wa##n3, hv.w, a3); }
      QUADS16(DA)
#undef DA
      float pre = (a0 + a1) + (a2 + a3);
      act0_s[g] = is_tanh_gate ? fast_tanh(pre) : fast_sigmoid(pre);
    }
    __syncthreads();  // barrier 2

    // deferred output store for t-1
    if (g == 0 && t > 0) out[(size_t)(t - 1) * DD + d] = part_s[0] + part_s[1] + boutd;

    // prefetch x-path for t+1
    if (PRE) {
      if (t + 1 < TT) gxn = gx[((size_t)d * TT + t + 1) * NG + g];
    } else if (g < XPAIRS && t + 1 < TT) {
      int tn = t + 1;
      if (g < SD / 2) {
        xa = shared_in[tn * SD + 2 * g];
        xb = shared_in[tn * SD + 2 * g + 1];
      } else {
        int k = 2 * (g - SD / 2);
        xa = perdev[((size_t)d * TT + tn) * PD + k];
        xb = perdev[((size_t)d * TT + tn) * PD + k + 1];
      }
    }

    // ---- phase 3: layer-0 cell update (threads 0..127) ----
    if (g < HH) {
      float ig = act0_s[g], fg = act0_s[g + 128], gg = act0_s[g + 256], og = act0_s[g + 384];
      c0 = __builtin_fmaf(fg, c0, ig * gg);
      float h0n = og * fast_tanh(c0);
      ((unsigned short*)h0_s)[g] = f16bits(h0n);
    }
    __syncthreads();  // barrier 3

    // ---- phase 4: gates1[g] = b1 + Wih1_row . h0_new + Whh1_row . h1 ----
    a0 = b1g; a1 = 0.f; a2 = 0.f; a3 = 0.f;
    {
      const uint4* h4 = (const uint4*)h0_s;
#define DI(q, n0, n1, n2, n3) { \
      uint4 hv = h4[q]; \
      a0 = dot2(wi##n0, hv.x, a0); a1 = dot2(wi##n1, hv.y, a1); \
      a2 = dot2(wi##n2, hv.z, a2); a3 = dot2(wi##n3, hv.w, a3); }
      QUADS16(DI)
#undef DI
      const uint4* g4 = (const uint4*)h1_s;
#define DH(q, n0, n1, n2, n3) { \
      uint4 hv = g4[q]; \
      a0 = dot2(wh##n0, hv.x, a0); a1 = dot2(wh##n1, hv.y, a1); \
      a2 = dot2(wh##n2, hv.z, a2); a3 = dot2(wh##n3, hv.w, a3); }
      QUADS16(DH)
#undef DH
      float pre = (a0 + a1) + (a2 + a3);
      act1_s[g] = is_tanh_gate ? fast_tanh(pre) : fast_sigmoid(pre);
    }
    __syncthreads();  // barrier 4

    // ---- phase 5: layer-1 cell update + output partial (threads 0..127) ----
    if (g < HH) {
      float ig = act1_s[g], fg = act1_s[g + 128], gg = act1_s[g + 256], og = act1_s[g + 384];
      c1 = __builtin_fmaf(fg, c1, ig * gg);
      float h1n = og * fast_tanh(c1);
      ((unsigned short*)h1_s)[g] = f16bits(h1n);
      float p = woutu * h1n;
#pragma unroll
      for (int off = 32; off > 0; off >>= 1) p += __shfl_down(p, off, 64);
      if (lane == 0) part_s[wave] = p;
    }
    gxc = gxn;
  }

  __syncthreads();
  if (g == 0) out[(size_t)(TT - 1) * DD + d] = part_s[0] + part_s[1] + boutd;
}

extern "C" void kernel_launch(void* const* d_in, const int* in_sizes, int n_in,
                              void* d_out, int out_size, void* d_ws, size_t ws_size,
                              hipStream_t stream) {
  const float* shared_in = (const float*)d_in[0];
  const float* perdev    = (const float*)d_in[1];
  const float* Wih0      = (const float*)d_in[2];
  const float* Whh0      = (const float*)d_in[3];
  const float* b0        = (const float*)d_in[4];
  const float* Wih1      = (const float*)d_in[5];
  const float* Whh1      = (const float*)d_in[6];
  const float* b1        = (const float*)d_in[7];
  const float* Wout      = (const float*)d_in[8];
  const float* bout      = (const float*)d_in[9];
  float* out = (float*)d_out;

  const size_t gx_bytes = (size_t)DD * TT * NG * sizeof(unsigned short);  // 128 MB
  if (ws_size >= gx_bytes) {
    unsigned short* gxp = (unsigned short*)d_ws;
    gx_kernel<<<dim3(TT / GXTB, DD), dim3(512), 0, stream>>>(shared_in, perdev, Wih0, b0, gxp);
    lstm_pipe_kernel<<<dim3(DD), dim3(768), 0, stream>>>(
        Whh0, Wih1, Whh1, b1, Wout, bout, gxp, out);
  } else {
    lstm_pd_kernel<false><<<dim3(DD), dim3(NG), 0, stream>>>(
        shared_in, perdev, Wih0, Whh0, b0, Wih1, Whh1, b1, Wout, bout, nullptr, out);
  }
}

// Round 2
// 5704.433 us; speedup vs baseline: 1.2837x; 1.2837x over previous
//
#include <hip/hip_runtime.h>

// Problem constants (match reference)
#define TT 4096   // sequence length (torch "batch" acting as time)
#define SD 64     // shared features
#define PD 8      // per-device features
#define DD 32     // devices
#define HH 128    // hidden
#define NG 512    // 4*H gate rows
#define XD 72     // S+P
#define XPAIRS 36 // packed f16x2 pairs of x
#define WROW 37   // padded row stride (uints) for W_ih0 in LDS (fallback path)
#define GXTB 16   // t-tile of the gx precompute kernel

typedef _Float16 h2 __attribute__((ext_vector_type(2)));
typedef unsigned uv16 __attribute__((ext_vector_type(16)));
typedef unsigned uv4 __attribute__((ext_vector_type(4)));

#if defined(__has_builtin)
#  if __has_builtin(__builtin_amdgcn_fdot2)
#    define USE_DOT2 1
#  endif
#endif

// ---- X-macro machinery ----
#define LIST16(X) \
  X(0) X(1) X(2) X(3) X(4) X(5) X(6) X(7) \
  X(8) X(9) X(10) X(11) X(12) X(13) X(14) X(15)
#define LIST32(X) LIST16(X) \
  X(16) X(17) X(18) X(19) X(20) X(21) X(22) X(23) \
  X(24) X(25) X(26) X(27) X(28) X(29) X(30) X(31)

#define LIST64(X) \
  X(0) X(1) X(2) X(3) X(4) X(5) X(6) X(7) \
  X(8) X(9) X(10) X(11) X(12) X(13) X(14) X(15) \
  X(16) X(17) X(18) X(19) X(20) X(21) X(22) X(23) \
  X(24) X(25) X(26) X(27) X(28) X(29) X(30) X(31) \
  X(32) X(33) X(34) X(35) X(36) X(37) X(38) X(39) \
  X(40) X(41) X(42) X(43) X(44) X(45) X(46) X(47) \
  X(48) X(49) X(50) X(51) X(52) X(53) X(54) X(55) \
  X(56) X(57) X(58) X(59) X(60) X(61) X(62) X(63)

#define QUADS16(X) \
  X(0,0,1,2,3)     X(1,4,5,6,7)     X(2,8,9,10,11)   X(3,12,13,14,15) \
  X(4,16,17,18,19) X(5,20,21,22,23) X(6,24,25,26,27) X(7,28,29,30,31) \
  X(8,32,33,34,35) X(9,36,37,38,39) X(10,40,41,42,43) X(11,44,45,46,47) \
  X(12,48,49,50,51) X(13,52,53,54,55) X(14,56,57,58,59) X(15,60,61,62,63)

// pack two floats into one uint of f16x2 (a = low element), RTE
__device__ __forceinline__ unsigned pack_h2(float a, float b) {
  unsigned short ua = __builtin_bit_cast(unsigned short, (_Float16)a);
  unsigned short ub = __builtin_bit_cast(unsigned short, (_Float16)b);
  return ((unsigned)ub << 16) | ua;
}
__device__ __forceinline__ unsigned short f16bits(float a) {
  return __builtin_bit_cast(unsigned short, (_Float16)a);
}
__device__ __forceinline__ float f16val(unsigned short u) {
  return (float)__builtin_bit_cast(_Float16, u);
}

// acc += dot(f16x2 w, f16x2 h), fp32 accumulate (v_dot2_f32_f16)
__device__ __forceinline__ float dot2(unsigned w, unsigned h, float acc) {
#ifdef USE_DOT2
  return __builtin_amdgcn_fdot2(__builtin_bit_cast(h2, w),
                                __builtin_bit_cast(h2, h), acc, false);
#else
  h2 wv = __builtin_bit_cast(h2, w), hv = __builtin_bit_cast(h2, h);
  return __builtin_fmaf((float)wv[1], (float)hv[1],
                        __builtin_fmaf((float)wv[0], (float)hv[0], acc));
#endif
}

__device__ __forceinline__ float fast_sigmoid(float x) {
  return 1.0f / (1.0f + __expf(-x));
}
__device__ __forceinline__ float fast_tanh(float x) {
  return 2.0f / (1.0f + __expf(-2.0f * x)) - 1.0f;
}

// DPP quad_perm cross-lane moves within 4-lane groups (pure VALU, no LDS):
// xor1 = quad_perm[1,0,3,2] = 0xB1 ; xor2 = quad_perm[2,3,0,1] = 0x4E
__device__ __forceinline__ float dppx1m(float x) {
  return __builtin_bit_cast(float,
      __builtin_amdgcn_update_dpp(0, __builtin_bit_cast(int, x), 0xB1, 0xF, 0xF, true));
}
__device__ __forceinline__ float dppx2m(float x) {
  return __builtin_bit_cast(float,
      __builtin_amdgcn_update_dpp(0, __builtin_bit_cast(int, x), 0x4E, 0xF, 0xF, true));
}
// sum across the 4-lane group (all lanes end with the group total)
__device__ __forceinline__ float bfly4(float x) {
  x += dppx1m(x);
  x += dppx2m(x);
  return x;
}

// ---------------------------------------------------------------------------
// gx precompute: gx2[d][t][u][gate] = f16( b0 + W_ih0_row . x[d][t] )
// TRANSPOSED inner layout (unit-major, gate-minor) so the main kernel's
// thread tid = u*4+lam reads its own gx value at a fully-coalesced offset.
// ---------------------------------------------------------------------------
__global__ __launch_bounds__(512)
void gx_kernel(const float* __restrict__ shared_in,  // [T, S]
               const float* __restrict__ perdev,     // [D, T, P]
               const float* __restrict__ Wih0,       // [D, 4H, S+P]
               const float* __restrict__ b0,         // [D, 4H]
               unsigned short* __restrict__ gx)      // [D, T, 128, 4] f16
{
  const int d = blockIdx.y;
  const int t0 = blockIdx.x * GXTB;
  const int g = threadIdx.x;          // gate row 0..511
  const int u = g & 127;              // hidden unit
  const int gate = g >> 7;            // 0..3 (i,f,g,o)

  __shared__ unsigned xs[GXTB * XPAIRS];  // x tile, packed f16x2

  const float* p = Wih0 + (size_t)(d * NG + g) * XD;
  uv16 w0, w1;
  uv4 w2;
#pragma unroll
  for (int j = 0; j < 16; ++j) w0[j] = pack_h2(p[2 * j], p[2 * j + 1]);
#pragma unroll
  for (int j = 0; j < 16; ++j) w1[j] = pack_h2(p[32 + 2 * j], p[33 + 2 * j]);
#pragma unroll
  for (int j = 0; j < 4; ++j) w2[j] = pack_h2(p[64 + 2 * j], p[65 + 2 * j]);
  const float b0g = b0[d * NG + g];

  for (int i = g; i < GXTB * XPAIRS; i += 512) {
    int r = i / XPAIRS, j = i - r * XPAIRS, t = t0 + r;
    float a, b;
    if (j < SD / 2) {
      a = shared_in[t * SD + 2 * j];
      b = shared_in[t * SD + 2 * j + 1];
    } else {
      int k = 2 * (j - SD / 2);
      a = perdev[((size_t)d * TT + t) * PD + k];
      b = perdev[((size_t)d * TT + t) * PD + k + 1];
    }
    xs[i] = pack_h2(a, b);
  }
  __syncthreads();

#define WJ(j) ((j) < 16 ? w0[(j)] : ((j) < 32 ? w1[(j)-16] : w2[(j)-32]))
  for (int tt = 0; tt < GXTB; ++tt) {
    const unsigned* xr = &xs[tt * XPAIRS];
    float a0 = b0g, a1 = 0.f, a2 = 0.f, a3 = 0.f;
#pragma unroll
    for (int j = 0; j < XPAIRS; j += 4) {
      a0 = dot2(WJ(j + 0), xr[j + 0], a0);
      a1 = dot2(WJ(j + 1), xr[j + 1], a1);
      a2 = dot2(WJ(j + 2), xr[j + 2], a2);
      a3 = dot2(WJ(j + 3), xr[j + 3], a3);
    }
    gx[((size_t)d * TT + t0 + tt) * NG + u * 4 + gate] = f16bits((a0 + a1) + (a2 + a3));
  }
#undef WJ
}

// ---------------------------------------------------------------------------
// Unit-local fused recurrence.
//
// 4-lane group owns hidden unit u = tid>>2; lane lam = tid&3 owns gate row
// u + lam*128 (i,f,g,o) and the K-slice [lam*K/4, (lam+1)*K/4) of the dots.
// Row partials are combined with a 2-step DPP quad butterfly, each lane
// activates its own gate, 4 DPP moves gather (i,f,g,o) to all lanes, and the
// cell update happens IN REGISTER — no act_s arrays, no gate->cell barrier.
//
// Epoch k computes layer0 for t=k (reads h0(k-1)) AND layer1 for t=k-1
// (reads h0(k-1), h1(k-2)) — both read only buffers written in epoch k-1,
// so ONE __syncthreads per step. All state double-buffered:
// reads from buf (k&1)^1, writes to buf k&1.
//
// LDS traffic/step/wave: 12 distributed ds_read_b128 (vs 48 broadcast
// before) + 3 small writes. Barriers/step: 1 (vs 3).
// ---------------------------------------------------------------------------
__global__ __attribute__((amdgpu_flat_work_group_size(512, 512), amdgpu_waves_per_eu(2, 2)))
void lstm_fused_kernel(const float* __restrict__ Whh0,        // [D, 4H, H]
                       const float* __restrict__ Wih1,        // [D, 4H, H]
                       const float* __restrict__ Whh1,        // [D, 4H, H]
                       const float* __restrict__ b1,          // [D, 4H]
                       const float* __restrict__ Wout,        // [D, H]
                       const float* __restrict__ bout,        // [D]
                       const unsigned short* __restrict__ gx, // [D, T, 128, 4] f16
                       float* __restrict__ out)               // [T, D]
{
  const int d = blockIdx.x;
  const int tid = threadIdx.x;
  const int lam = tid & 3;
  const int u = tid >> 2;          // hidden unit 0..127
  const bool lp = (lam < 2);

  __shared__ __align__(16) unsigned h0_s[2][HH / 2];  // h0 packed f16x2, dbuf
  __shared__ __align__(16) unsigned h1_s[2][HH / 2];  // h1 packed f16x2, dbuf
  __shared__ float part2_s[2][HH];                    // per-unit wout*h1 partials

  // ---- weight registers: 192 independent scalars ----
  // L0: rows A..D = Whh0 rows (u + r*128), cols [lam*32, lam*32+32)  (16 uints each)
  // L1: rows E..H = (lam<2 ? Wih1 : Whh1) rows (u + r*128), cols [(lam&1)*64, +64) (32 uints each)
#define DWA(n) unsigned wA##n;
  LIST16(DWA)
#undef DWA
#define DWB(n) unsigned wB##n;
  LIST16(DWB)
#undef DWB
#define DWC(n) unsigned wC##n;
  LIST16(DWC)
#undef DWC
#define DWD(n) unsigned wD##n;
  LIST16(DWD)
#undef DWD
#define DWE(n) unsigned wE##n;
  LIST32(DWE)
#undef DWE
#define DWF(n) unsigned wF##n;
  LIST32(DWF)
#undef DWF
#define DWG(n) unsigned wG##n;
  LIST32(DWG)
#undef DWG
#define DWH(n) unsigned wH##n;
  LIST32(DWH)
#undef DWH
  {
    const float* p = Whh0 + ((size_t)d * NG + u) * HH + lam * 32;
#define LWA(n) wA##n = pack_h2(p[2 * (n)], p[2 * (n) + 1]);
    LIST16(LWA)
#undef LWA
    p += (size_t)128 * HH;
#define LWB(n) wB##n = pack_h2(p[2 * (n)], p[2 * (n) + 1]);
    LIST16(LWB)
#undef LWB
    p += (size_t)128 * HH;
#define LWC(n) wC##n = pack_h2(p[2 * (n)], p[2 * (n) + 1]);
    LIST16(LWC)
#undef LWC
    p += (size_t)128 * HH;
#define LWD(n) wD##n = pack_h2(p[2 * (n)], p[2 * (n) + 1]);
    LIST16(LWD)
#undef LWD
    const float* q = (lp ? Wih1 : Whh1) + ((size_t)d * NG + u) * HH + (lam & 1) * 64;
#define LWE(n) wE##n = pack_h2(q[2 * (n)], q[2 * (n) + 1]);
    LIST32(LWE)
#undef LWE
    q += (size_t)128 * HH;
#define LWF(n) wF##n = pack_h2(q[2 * (n)], q[2 * (n) + 1]);
    LIST32(LWF)
#undef LWF
    q += (size_t)128 * HH;
#define LWG(n) wG##n = pack_h2(q[2 * (n)], q[2 * (n) + 1]);
    LIST32(LWG)
#undef LWG
    q += (size_t)128 * HH;
#define LWH(n) wH##n = pack_h2(q[2 * (n)], q[2 * (n) + 1]);
    LIST32(LWH)
#undef LWH
  }

  // per-lane activation consts: lane 2 (g gate) is tanh = fma(1/(1+e^-2x), 2, -1);
  // others sigmoid = fma(1/(1+e^-x), 1, 0). scale == mul for both.
  const float actS = (lam == 2) ? 2.f : 1.f;
  const float actA = (lam == 2) ? -1.f : 0.f;
  const float b1sel = b1[(size_t)d * NG + u + lam * 128];
  const float woutu = Wout[(size_t)d * HH + u];
  const float boutd = bout[d];
  float c0 = 0.f, c1 = 0.f;   // maintained redundantly on all 4 lanes of the group

  if (tid < HH / 2) {
    h0_s[0][tid] = 0u; h0_s[1][tid] = 0u;
    h1_s[0][tid] = 0u; h1_s[1][tid] = 0u;
  }
  if (tid < HH) { part2_s[0][tid] = 0.f; part2_s[1][tid] = 0.f; }

  // gx prefetch: tid-coalesced (layout is [t][u*4+gate], tid == u*4+lam)
  const unsigned short* gp = gx + (size_t)d * TT * NG + tid;
  unsigned short gxc = gp[0], gxn = 0;

  __syncthreads();

  // epoch k: layer0 for t=k (k<TT), layer1 for t=k-1 (k>=1), out for t=k-2 (k>=2)
  for (int k = 0; k <= TT; ++k) {
    const int rb = (k & 1) ^ 1;   // read buffer (written epoch k-1)
    const int wb = k & 1;         // write buffer

    if (k + 1 < TT) gxn = gp[(size_t)(k + 1) * NG];

    // ---- deferred output for t=k-2 (reads partials written epoch k-1) ----
    if (k >= 2 && tid < 64) {
      float pv = part2_s[rb][tid] + part2_s[rb][tid + 64];
#pragma unroll
      for (int off = 32; off > 0; off >>= 1) pv += __shfl_xor(pv, off, 64);
      if (tid == 0) out[(size_t)(k - 2) * DD + d] = pv + boutd;
    }

    // ---- layer 0 for t=k: gates0 = gx(k) + Whh0 . h0(k-1) ----
    if (k < TT) {
      const uint4* hp = (const uint4*)h0_s[rb];
      uint4 q0 = hp[lam * 4 + 0], q1 = hp[lam * 4 + 1],
            q2 = hp[lam * 4 + 2], q3 = hp[lam * 4 + 3];
      float aA = 0.f, aB = 0.f, aC = 0.f, aD = 0.f;
#define A0S(j, HV) { aA = dot2(wA##j, HV, aA); aB = dot2(wB##j, HV, aB); \
                     aC = dot2(wC##j, HV, aC); aD = dot2(wD##j, HV, aD); }
      A0S(0, q0.x)  A0S(1, q0.y)  A0S(2, q0.z)  A0S(3, q0.w)
      A0S(4, q1.x)  A0S(5, q1.y)  A0S(6, q1.z)  A0S(7, q1.w)
      A0S(8, q2.x)  A0S(9, q2.y)  A0S(10, q2.z) A0S(11, q2.w)
      A0S(12, q3.x) A0S(13, q3.y) A0S(14, q3.z) A0S(15, q3.w)
#undef A0S
      aA = bfly4(aA); aB = bfly4(aB); aC = bfly4(aC); aD = bfly4(aD);
      float pre = (lam == 0) ? aA : (lam == 1) ? aB : (lam == 2) ? aC : aD;
      pre += f16val(gxc);                       // gx includes b0
      float e = __expf(-actS * pre);
      float act = __builtin_fmaf(1.f / (1.f + e), actS, actA);
      // gather (i,f,g,o) onto all 4 lanes via DPP
      float v1 = dppx1m(act);
      float lo = (lam & 1) ? v1 : act;          // pair's even row (i or g)
      float hi = (lam & 1) ? act : v1;          // pair's odd row  (f or o)
      float lo2 = dppx2m(lo);
      float hi2 = dppx2m(hi);
      float ig = lp ? lo : lo2;
      float fg = lp ? hi : hi2;
      float gg = lp ? lo2 : lo;
      float og = lp ? hi2 : hi;
      c0 = __builtin_fmaf(fg, c0, ig * gg);
      float h0n = og * fast_tanh(c0);
      if (lam == 0) ((unsigned short*)h0_s[wb])[u] = f16bits(h0n);
    }

    // ---- layer 1 for t=k-1: gates1 = b1 + Wih1 . h0(k-1) + Whh1 . h1(k-2) ----
    if (k >= 1) {
      const uint4* bp = (const uint4*)(lp ? h0_s[rb] : h1_s[rb]);
      const int bo = (lam & 1) * 8;
      uint4 r0 = bp[bo + 0], r1 = bp[bo + 1], r2 = bp[bo + 2], r3 = bp[bo + 3],
            r4 = bp[bo + 4], r5 = bp[bo + 5], r6 = bp[bo + 6], r7 = bp[bo + 7];
      float aE = 0.f, aF = 0.f, aG = 0.f, aH = 0.f;
#define B0S(j, HV) { aE = dot2(wE##j, HV, aE); aF = dot2(wF##j, HV, aF); \
                     aG = dot2(wG##j, HV, aG); aH = dot2(wH##j, HV, aH); }
      B0S(0, r0.x)  B0S(1, r0.y)  B0S(2, r0.z)  B0S(3, r0.w)
      B0S(4, r1.x)  B0S(5, r1.y)  B0S(6, r1.z)  B0S(7, r1.w)
      B0S(8, r2.x)  B0S(9, r2.y)  B0S(10, r2.z) B0S(11, r2.w)
      B0S(12, r3.x) B0S(13, r3.y) B0S(14, r3.z) B0S(15, r3.w)
      B0S(16, r4.x) B0S(17, r4.y) B0S(18, r4.z) B0S(19, r4.w)
      B0S(20, r5.x) B0S(21, r5.y) B0S(22, r5.z) B0S(23, r5.w)
      B0S(24, r6.x) B0S(25, r6.y) B0S(26, r6.z) B0S(27, r6.w)
      B0S(28, r7.x) B0S(29, r7.y) B0S(30, r7.z) B0S(31, r7.w)
#undef B0S
      aE = bfly4(aE); aF = bfly4(aF); aG = bfly4(aG); aH = bfly4(aH);
      float pre = (lam == 0) ? aE : (lam == 1) ? aF : (lam == 2) ? aG : aH;
      pre += b1sel;
      float e = __expf(-actS * pre);
      float act = __builtin_fmaf(1.f / (1.f + e), actS, actA);
      float v1 = dppx1m(act);
      float lo = (lam & 1) ? v1 : act;
      float hi = (lam & 1) ? act : v1;
      float lo2 = dppx2m(lo);
      float hi2 = dppx2m(hi);
      float ig = lp ? lo : lo2;
      float fg = lp ? hi : hi2;
      float gg = lp ? lo2 : lo;
      float og = lp ? hi2 : hi;
      c1 = __builtin_fmaf(fg, c1, ig * gg);
      float h1n = og * fast_tanh(c1);
      if (lam == 0) {
        ((unsigned short*)h1_s[wb])[u] = f16bits(h1n);
        part2_s[wb][u] = woutu * h1n;
      }
    }

    __syncthreads();   // single barrier per step
    gxc = gxn;
  }

  // epilogue: out for t=TT-1 (partials written at epoch TT, buf TT&1)
  if (tid < 64) {
    float pv = part2_s[TT & 1][tid] + part2_s[TT & 1][tid + 64];
#pragma unroll
    for (int off = 32; off > 0; off >>= 1) pv += __shfl_xor(pv, off, 64);
    if (tid == 0) out[(size_t)(TT - 1) * DD + d] = pv + boutd;
  }
}

// ---------------------------------------------------------------------------
// Fallback (no workspace): previous-session kernel, non-PRE path only.
// ---------------------------------------------------------------------------
template <bool PRE>
__global__ __attribute__((amdgpu_flat_work_group_size(512, 512), amdgpu_waves_per_eu(2, 2)))
void lstm_pd_kernel(const float* __restrict__ shared_in,   // [T, S]
                    const float* __restrict__ perdev,      // [D, T, P]
                    const float* __restrict__ Wih0,        // [D, 4H, S+P]
                    const float* __restrict__ Whh0,        // [D, 4H, H]
                    const float* __restrict__ b0,          // [D, 4H]
                    const float* __restrict__ Wih1,        // [D, 4H, H]
                    const float* __restrict__ Whh1,        // [D, 4H, H]
                    const float* __restrict__ b1,          // [D, 4H]
                    const float* __restrict__ Wout,        // [D, H]
                    const float* __restrict__ bout,        // [D]
                    const unsigned short* __restrict__ gx, // unused in fallback
                    float* __restrict__ out)               // [T, D]
{
  const int d = blockIdx.x;        // device
  const int g = threadIdx.x;       // gate row 0..511
  const int lane = g & 63;
  const int wave = g >> 6;

  __shared__ float act0_s[NG];
  __shared__ float act1_s[NG];
  __shared__ __align__(16) unsigned h0_s[HH / 2];      // h0 packed f16x2
  __shared__ __align__(16) unsigned h1_s[HH / 2];      // h1 packed f16x2
  __shared__ __align__(16) unsigned x_s[PRE ? 4 : (XPAIRS + 4)];
  __shared__ unsigned wih0_s[PRE ? 1 : (NG * WROW)];
  __shared__ float part_s[2];

  // ---- weight registers: 192 independent scalars ----
#define DW(n) unsigned wa##n, wi##n, wh##n;
  LIST64(DW)
#undef DW
  {
    const float* pa = Whh0 + (size_t)(d * NG + g) * HH;
    const float* pi = Wih1 + (size_t)(d * NG + g) * HH;
    const float* ph = Whh1 + (size_t)(d * NG + g) * HH;
#define SW(n) wa##n = pack_h2(pa[2 * (n)], pa[2 * (n) + 1]); \
              wi##n = pack_h2(pi[2 * (n)], pi[2 * (n) + 1]); \
              wh##n = pack_h2(ph[2 * (n)], ph[2 * (n) + 1]);
    LIST64(SW)
#undef SW
  }

  float b0g = 0.f;
  if (!PRE) {
    const float* p = Wih0 + (size_t)(d * NG + g) * XD;
    for (int j = 0; j < XPAIRS; ++j) wih0_s[g * WROW + j] = pack_h2(p[2 * j], p[2 * j + 1]);
    b0g = b0[d * NG + g];
  }
  const float b1g = b1[d * NG + g];
  const bool is_tanh_gate = ((g >> 7) == 2);  // rows 256..383 = candidate gate
  float c0 = 0.f, c1 = 0.f;
  const float woutu = (g < HH) ? Wout[d * HH + g] : 0.f;
  const float boutd = bout[d];

  if (g < HH / 2) { h0_s[g] = 0u; h1_s[g] = 0u; }

  // prefetch x-path for t=0
  float xa = 0.f, xb = 0.f;
  if (!PRE && g < XPAIRS) {
    if (g < SD / 2) {
      xa = shared_in[0 * SD + 2 * g];
      xb = shared_in[0 * SD + 2 * g + 1];
    } else {
      int k = 2 * (g - SD / 2);
      xa = perdev[((size_t)d * TT + 0) * PD + k];
      xb = perdev[((size_t)d * TT + 0) * PD + k + 1];
    }
  }

  __syncthreads();

  for (int t = 0; t < TT; ++t) {
    if (!PRE) {
      if (g < XPAIRS) x_s[g] = pack_h2(xa, xb);
      __syncthreads();  // barrier 1 (fallback only)
    }

    // ---- phase 2: gates0[g] = b0 + Wih0_row . x + Whh0_row . h0 ----
    float a0 = b0g, a1 = 0.f, a2 = 0.f, a3 = 0.f;
    if (!PRE) {
      const unsigned* wrow = &wih0_s[g * WROW];
#pragma unroll
      for (int j = 0; j < XPAIRS; j += 4) {
        a0 = dot2(wrow[j + 0], x_s[j + 0], a0);
        a1 = dot2(wrow[j + 1], x_s[j + 1], a1);
        a2 = dot2(wrow[j + 2], x_s[j + 2], a2);
        a3 = dot2(wrow[j + 3], x_s[j + 3], a3);
      }
    }
    {
      const uint4* h4 = (const uint4*)h0_s;
#define DA(q, n0, n1, n2, n3) { \
      uint4 hv = h4[q]; \
      a0 = dot2(wa##n0, hv.x, a0); a1 = dot2(wa##n1, hv.y, a1); \
      a2 = dot2(wa##n2, hv.z, a2); a3 = dot2(wa##n3, hv.w, a3); }
      QUADS16(DA)
#undef DA
      float pre = (a0 + a1) + (a2 + a3);
      act0_s[g] = is_tanh_gate ? fast_tanh(pre) : fast_sigmoid(pre);
    }
    __syncthreads();  // barrier 2

    // deferred output store for t-1
    if (g == 0 && t > 0) out[(size_t)(t - 1) * DD + d] = part_s[0] + part_s[1] + boutd;

    // prefetch x-path for t+1
    if (!PRE && g < XPAIRS && t + 1 < TT) {
      int tn = t + 1;
      if (g < SD / 2) {
        xa = shared_in[tn * SD + 2 * g];
        xb = shared_in[tn * SD + 2 * g + 1];
      } else {
        int k = 2 * (g - SD / 2);
        xa = perdev[((size_t)d * TT + tn) * PD + k];
        xb = perdev[((size_t)d * TT + tn) * PD + k + 1];
      }
    }

    // ---- phase 3: layer-0 cell update (threads 0..127) ----
    if (g < HH) {
      float ig = act0_s[g], fg = act0_s[g + 128], gg = act0_s[g + 256], og = act0_s[g + 384];
      c0 = __builtin_fmaf(fg, c0, ig * gg);
      float h0n = og * fast_tanh(c0);
      ((unsigned short*)h0_s)[g] = f16bits(h0n);
    }
    __syncthreads();  // barrier 3

    // ---- phase 4: gates1[g] = b1 + Wih1_row . h0_new + Whh1_row . h1 ----
    a0 = b1g; a1 = 0.f; a2 = 0.f; a3 = 0.f;
    {
      const uint4* h4 = (const uint4*)h0_s;
#define DI(q, n0, n1, n2, n3) { \
      uint4 hv = h4[q]; \
      a0 = dot2(wi##n0, hv.x, a0); a1 = dot2(wi##n1, hv.y, a1); \
      a2 = dot2(wi##n2, hv.z, a2); a3 = dot2(wi##n3, hv.w, a3); }
      QUADS16(DI)
#undef DI
      const uint4* g4 = (const uint4*)h1_s;
#define DH(q, n0, n1, n2, n3) { \
      uint4 hv = g4[q]; \
      a0 = dot2(wh##n0, hv.x, a0); a1 = dot2(wh##n1, hv.y, a1); \
      a2 = dot2(wh##n2, hv.z, a2); a3 = dot2(wh##n3, hv.w, a3); }
      QUADS16(DH)
#undef DH
      float pre = (a0 + a1) + (a2 + a3);
      act1_s[g] = is_tanh_gate ? fast_tanh(pre) : fast_sigmoid(pre);
    }
    __syncthreads();  // barrier 4

    // ---- phase 5: layer-1 cell update + output partial (threads 0..127) ----
    if (g < HH) {
      float ig = act1_s[g], fg = act1_s[g + 128], gg = act1_s[g + 256], og = act1_s[g + 384];
      c1 = __builtin_fmaf(fg, c1, ig * gg);
      float h1n = og * fast_tanh(c1);
      ((unsigned short*)h1_s)[g] = f16bits(h1n);
      float p = woutu * h1n;
#pragma unroll
      for (int off = 32; off > 0; off >>= 1) p += __shfl_down(p, off, 64);
      if (lane == 0) part_s[wave] = p;
    }
  }

  __syncthreads();
  if (g == 0) out[(size_t)(TT - 1) * DD + d] = part_s[0] + part_s[1] + boutd;
}

extern "C" void kernel_launch(void* const* d_in, const int* in_sizes, int n_in,
                              void* d_out, int out_size, void* d_ws, size_t ws_size,
                              hipStream_t stream) {
  const float* shared_in = (const float*)d_in[0];
  const float* perdev    = (const float*)d_in[1];
  const float* Wih0      = (const float*)d_in[2];
  const float* Whh0      = (const float*)d_in[3];
  const float* b0        = (const float*)d_in[4];
  const float* Wih1      = (const float*)d_in[5];
  const float* Whh1      = (const float*)d_in[6];
  const float* b1        = (const float*)d_in[7];
  const float* Wout      = (const float*)d_in[8];
  const float* bout      = (const float*)d_in[9];
  float* out = (float*)d_out;

  const size_t gx_bytes = (size_t)DD * TT * NG * sizeof(unsigned short);  // 128 MB
  if (ws_size >= gx_bytes) {
    unsigned short* gxp = (unsigned short*)d_ws;
    gx_kernel<<<dim3(TT / GXTB, DD), dim3(512), 0, stream>>>(shared_in, perdev, Wih0, b0, gxp);
    lstm_fused_kernel<<<dim3(DD), dim3(NG), 0, stream>>>(
        Whh0, Wih1, Whh1, b1, Wout, bout, gxp, out);
  } else {
    lstm_pd_kernel<false><<<dim3(DD), dim3(NG), 0, stream>>>(
        shared_in, perdev, Wih0, Whh0, b0, Wih1, Whh1, b1, Wout, bout, nullptr, out);
  }
}